// Round 1
// 19490.678 us; speedup vs baseline: 1.0019x; 1.0019x over previous
//
#include <hip/hip_runtime.h>
#include <stdint.h>

#define LSTEPS 2048
#define NB 32
#define IS 128
#define HS 1024
#define NGROUPS 8      // one per XCD (blockIdx % 8 round-robin)
#define WPG 32         // workgroups per group
#define BPG 4          // batch elements per group
#define CPW 32         // hidden columns per WG
#define NTHREADS 256
#define FLAG_SLOTS 64  // flag ring; exact-value match makes reuse safe (skew <= 1 step)

__global__ __launch_bounds__(NTHREADS, 1)   // 1 wave/EU min -> full 512-VGPR budget
void reservoir_scan(const float* __restrict__ x,
                    const float* __restrict__ h_init,
                    const float* __restrict__ W_in,
                    const float* __restrict__ bias,
                    const float* __restrict__ W_h,
                    float* __restrict__ out,
                    unsigned int* __restrict__ flags) {
  const int b    = blockIdx.x;
  const int g    = b & 7;     // group (likely = XCD)
  const int wg   = b >> 3;    // 0..31 within group
  const int tid  = threadIdx.x;
  const int w    = tid >> 6;  // wave 0..3  (owns 8 hidden cols)
  const int lane = tid & 63;  // k-split lane
  const int jbase = wg * CPW; // hidden-col base of this WG
  const int nbase = g * BPG;  // batch base of this group

  // LDS region A (8704 floats), phase-multiplexed:
  //   stage/compute phase: h_lds [4][1024] + x_lds [4][128]
  //   reduce phase:        red [128][68]  (pad 68 -> conflict-free b128 reads)
  // W_h / W_in no longer touch LDS: they live in registers for the whole scan.
  __shared__ __align__(16) float smem[8704];
  float* const h_lds = smem;          // 4096 floats
  float* const x_lds = smem + 4096;   // 512 floats
  float* const red   = smem;          // 8704 floats

  // ---- persistent weights in registers (loaded once, coalesced) ----
  // wreg[u][jj] = W_h[jbase + w*8 + jj][u*256 + lane*4 .. +3]   (128 VGPRs)
  float4 wreg[4][8];
  #pragma unroll
  for (int u = 0; u < 4; ++u)
    #pragma unroll
    for (int jj = 0; jj < 8; ++jj)
      wreg[u][jj] = *(const float4*)&W_h[(size_t)(jbase + w * 8 + jj) * HS + u * 256 + lane * 4];

  // wireg[jj] = W_in[jbase + w*8 + jj][lane*2 .. +1]   (16 VGPRs)
  float2 wireg[8];
  #pragma unroll
  for (int jj = 0; jj < 8; ++jj)
    wireg[jj] = *(const float2*)&W_in[(size_t)(jbase + w * 8 + jj) * IS + lane * 2];

  // Reducer threads (tid<128) own output (n = tid>>5, jc = tid&31).
  const float my_bias = (tid < 128) ? bias[jbase + (tid & 31)] : 0.f;

  #pragma unroll 1
  for (int t = 0; t < LSTEPS; ++t) {
    // ---- wait for all 32 producers of step t-1 (wave 0 spins) ----
    if (t > 0) {
      if (w == 0) {
        const unsigned int target = (unsigned int)t;  // value written for step t-1
        const unsigned int* fl =
            flags + ((size_t)(g * FLAG_SLOTS + ((t - 1) & (FLAG_SLOTS - 1))) << 5);
        for (;;) {
          unsigned int v = (lane < WPG)
              ? __hip_atomic_load(&fl[lane], __ATOMIC_RELAXED, __HIP_MEMORY_SCOPE_AGENT)
              : target;
          if (__all(v == target)) break;
          __builtin_amdgcn_s_sleep(1);
        }
      }
    }
    __syncthreads();  // (a) spin done; also protects region A vs prev reduce-reads

    // ---- stage h (16 KB) and x (2 KB) into LDS ----
    if (t > 0) {
      const float* hsrc = out + (size_t)((t - 1) * NB + nbase) * HS;
      for (int e = tid; e < BPG * HS; e += NTHREADS)
        h_lds[e] = __hip_atomic_load(&hsrc[e], __ATOMIC_RELAXED, __HIP_MEMORY_SCOPE_AGENT);
    } else {
      const float* hsrc = h_init + (size_t)nbase * HS;
      for (int e = tid; e < BPG * HS; e += NTHREADS)
        h_lds[e] = hsrc[e];
    }
    {
      const float* xsrc = x + (size_t)(t * NB + nbase) * IS;
      for (int e = tid; e < BPG * IS; e += NTHREADS)
        x_lds[e] = xsrc[e];
    }
    __syncthreads();  // (b) staging visible

    // ---- partial dot products: acc[jj][nn], k split across lanes ----
    float acc[8][4];
    #pragma unroll
    for (int jj = 0; jj < 8; ++jj)
      #pragma unroll
      for (int nn = 0; nn < 4; ++nn) acc[jj][nn] = 0.f;

    // input projection: i = lane*2 .. lane*2+1  (weights from registers)
    {
      float2 xv[4];
      #pragma unroll
      for (int nn = 0; nn < 4; ++nn)
        xv[nn] = *(const float2*)&x_lds[nn * IS + lane * 2];
      #pragma unroll
      for (int jj = 0; jj < 8; ++jj) {
        const float2 wv = wireg[jj];
        #pragma unroll
        for (int nn = 0; nn < 4; ++nn)
          acc[jj][nn] += wv.x * xv[nn].x + wv.y * xv[nn].y;
      }
    }

    // recurrent part: k = u*256 + lane*4 (weights from registers, h from LDS)
    #pragma unroll
    for (int u = 0; u < 4; ++u) {
      const int k = u * 256 + lane * 4;
      float4 hv[4];
      #pragma unroll
      for (int nn = 0; nn < 4; ++nn)
        hv[nn] = *(const float4*)&h_lds[nn * HS + k];
      #pragma unroll
      for (int jj = 0; jj < 8; ++jj) {
        const float4 wv = wreg[u][jj];
        #pragma unroll
        for (int nn = 0; nn < 4; ++nn) {
          acc[jj][nn] += wv.x * hv[nn].x;
          acc[jj][nn] += wv.y * hv[nn].y;
          acc[jj][nn] += wv.z * hv[nn].z;
          acc[jj][nn] += wv.w * hv[nn].w;
        }
      }
    }

    __syncthreads();  // (c) h_lds/x_lds reads done -> region A becomes 'red'

    // ---- cross-lane reduction via LDS ----
    #pragma unroll
    for (int jj = 0; jj < 8; ++jj)
      #pragma unroll
      for (int nn = 0; nn < 4; ++nn)
        red[(size_t)(nn * 32 + w * 8 + jj) * 68 + lane] = acc[jj][nn];
    __syncthreads();  // (d)

    if (tid < 128) {
      const int nn = tid >> 5;
      const int jc = tid & 31;
      float s = 0.f;
      const float* r = &red[(size_t)tid * 68];
      #pragma unroll
      for (int q = 0; q < 16; ++q) {
        const float4 v = *(const float4*)&r[q * 4];
        s += (v.x + v.y) + (v.z + v.w);
      }
      s = tanhf(s + my_bias);
      // d_out is both the result and the h-exchange medium.
      float* dst = out + (size_t)(t * NB + nbase + nn) * HS + jbase + jc;
      __hip_atomic_store(dst, s, __ATOMIC_RELAXED, __HIP_MEMORY_SCOPE_AGENT);
    }
    __syncthreads();  // (e) drains vmcnt(0): all slice stores complete before flag

    if (tid == 0) {
      __hip_atomic_store(
          &flags[((size_t)(g * FLAG_SLOTS + (t & (FLAG_SLOTS - 1))) << 5) + wg],
          (unsigned int)(t + 1), __ATOMIC_RELEASE, __HIP_MEMORY_SCOPE_AGENT);
    }
  }
}

extern "C" void kernel_launch(void* const* d_in, const int* in_sizes, int n_in,
                              void* d_out, int out_size, void* d_ws, size_t ws_size,
                              hipStream_t stream) {
  const float* x     = (const float*)d_in[0];
  const float* h0    = (const float*)d_in[1];
  const float* W_in  = (const float*)d_in[2];
  const float* bias  = (const float*)d_in[3];
  const float* W_h   = (const float*)d_in[4];
  float* out = (float*)d_out;
  unsigned int* flags = (unsigned int*)d_ws;  // 8*64*32*4 = 64 KB of ws; poison-safe

  hipLaunchKernelGGL(reservoir_scan, dim3(NGROUPS * WPG), dim3(NTHREADS), 0, stream,
                     x, h0, W_in, bias, W_h, out, flags);
}

// Round 2
// 19356.633 us; speedup vs baseline: 1.0088x; 1.0069x over previous
//
#include <hip/hip_runtime.h>
#include <stdint.h>

#define LSTEPS 2048
#define NB 32
#define IS 128
#define HS 1024
#define NGROUPS 8      // one per XCD (blockIdx % 8 round-robin)
#define WPG 32         // workgroups per group
#define BPG 4          // batch elements per group
#define CPW 32         // hidden columns per WG
#define NTHREADS 256
#define FLAG_SLOTS 64  // flag ring; exact-value match makes reuse safe (skew <= 1 step)

__global__ __launch_bounds__(NTHREADS, 1)
void reservoir_scan(const float* __restrict__ x,
                    const float* __restrict__ h_init,
                    const float* __restrict__ W_in,
                    const float* __restrict__ bias,
                    const float* __restrict__ W_h,
                    float* __restrict__ out,
                    unsigned int* __restrict__ flags) {
  const int b    = blockIdx.x;
  const int g    = b & 7;     // group (likely = XCD)
  const int wg   = b >> 3;    // 0..31 within group
  const int tid  = threadIdx.x;
  const int w    = tid >> 6;  // wave 0..3  (owns 8 hidden cols)
  const int lane = tid & 63;  // k-split lane
  const int jbase = wg * CPW; // hidden-col base of this WG
  const int nbase = g * BPG;  // batch base of this group

  // LDS (149.5 KB of the 160 KB/CU, 1 WG/CU):
  //   wh_lds [32][1024]  128 KB  -- this WG's W_h row slice, resident all steps
  //   h_lds  [4][1024]    16 KB  -- h(t-1) exchange buffer
  //   x_lds  [4][128]      2 KB
  // No 'red' region: cross-lane reduction is done with shuffles.
  __shared__ __align__(16) float wh_lds[CPW * HS];
  __shared__ __align__(16) float h_lds[BPG * HS];
  __shared__ __align__(16) float x_lds[BPG * IS];

  // ---- stage W_h slice into LDS once (coalesced float4); visible at barrier (b) of t=0 ----
  for (int e = tid * 4; e < CPW * HS; e += NTHREADS * 4)
    *(float4*)&wh_lds[e] = *(const float4*)&W_h[(size_t)jbase * HS + e];

  // W_in fragment per lane (16 VGPRs; if the compiler sinks these reloads into the
  // loop it is only 64 B/thread/step from L2 -- acceptable either way).
  float2 wireg[8];
  #pragma unroll
  for (int jj = 0; jj < 8; ++jj)
    wireg[jj] = *(const float2*)&W_in[(size_t)(jbase + w * 8 + jj) * IS + lane * 2];

  // After the butterfly reduce, lane L holds output index i = L&31: nn = i>>3, jj = i&7.
  const int onn = (lane & 31) >> 3;
  const int ojj = lane & 7;
  const float my_bias = bias[jbase + w * 8 + ojj];

  #pragma unroll 1
  for (int t = 0; t < LSTEPS; ++t) {
    // ---- stage x(t) early: independent of flags, region free since barrier (e) of t-1 ----
    {
      const float* xsrc = x + (size_t)(t * NB + nbase) * IS;
      for (int e = tid; e < BPG * IS; e += NTHREADS)
        x_lds[e] = xsrc[e];
    }

    // ---- wait for all 32 producers of step t-1 (ALL waves spin; no barrier needed after) ----
    if (t > 0) {
      const unsigned int target = (unsigned int)t;  // value written for step t-1
      const unsigned int* fl =
          flags + ((size_t)(g * FLAG_SLOTS + ((t - 1) & (FLAG_SLOTS - 1))) << 5);
      for (;;) {
        unsigned int v = (lane < WPG)
            ? __hip_atomic_load(&fl[lane], __ATOMIC_RELAXED, __HIP_MEMORY_SCOPE_AGENT)
            : target;
        if (__all(v == target)) break;
        __builtin_amdgcn_s_sleep(1);
      }
      const float* hsrc = out + (size_t)((t - 1) * NB + nbase) * HS;
      for (int e = tid; e < BPG * HS; e += NTHREADS)
        h_lds[e] = __hip_atomic_load(&hsrc[e], __ATOMIC_RELAXED, __HIP_MEMORY_SCOPE_AGENT);
    } else {
      const float* hsrc = h_init + (size_t)nbase * HS;
      for (int e = tid; e < BPG * HS; e += NTHREADS)
        h_lds[e] = hsrc[e];
    }
    __syncthreads();  // (b) h_lds + x_lds (+ wh_lds at t=0) visible to all waves

    // ---- partial dot products: acc[jj][nn], k split across lanes ----
    float acc[8][4];
    #pragma unroll
    for (int jj = 0; jj < 8; ++jj)
      #pragma unroll
      for (int nn = 0; nn < 4; ++nn) acc[jj][nn] = 0.f;

    // input projection: i = lane*2 .. lane*2+1
    {
      float2 xv[4];
      #pragma unroll
      for (int nn = 0; nn < 4; ++nn)
        xv[nn] = *(const float2*)&x_lds[nn * IS + lane * 2];
      #pragma unroll
      for (int jj = 0; jj < 8; ++jj) {
        const float2 wv = wireg[jj];
        #pragma unroll
        for (int nn = 0; nn < 4; ++nn)
          acc[jj][nn] += wv.x * xv[nn].x + wv.y * xv[nn].y;
      }
    }

    // recurrent part: k = u*256 + lane*4; W_h from LDS (conflict-free contiguous b128)
    #pragma unroll
    for (int u = 0; u < 4; ++u) {
      const int k = u * 256 + lane * 4;
      float4 hv[4];
      #pragma unroll
      for (int nn = 0; nn < 4; ++nn)
        hv[nn] = *(const float4*)&h_lds[nn * HS + k];
      #pragma unroll
      for (int jj = 0; jj < 8; ++jj) {
        const float4 wv = *(const float4*)&wh_lds[(w * 8 + jj) * HS + k];
        #pragma unroll
        for (int nn = 0; nn < 4; ++nn) {
          acc[jj][nn] += wv.x * hv[nn].x;
          acc[jj][nn] += wv.y * hv[nn].y;
          acc[jj][nn] += wv.z * hv[nn].z;
          acc[jj][nn] += wv.w * hv[nn].w;
        }
      }
    }

    // ---- butterfly multi-value reduction: 32 values x 64 lanes -> lane L holds i = L&31 ----
    // Invariant before stage s: slot q holds index i with bits0..s-1(i)=bits0..s-1(lane), q=i>>s.
    float a0[32];
    #pragma unroll
    for (int jj = 0; jj < 8; ++jj)
      #pragma unroll
      for (int nn = 0; nn < 4; ++nn)
        a0[nn * 8 + jj] = acc[jj][nn];

    float a1[16];
    {
      const int bit = lane & 1;
      #pragma unroll
      for (int q = 0; q < 16; ++q) {
        const float give = bit ? a0[2 * q] : a0[2 * q + 1];
        const float keep = bit ? a0[2 * q + 1] : a0[2 * q];
        a1[q] = keep + __shfl_xor(give, 1);
      }
    }
    float a2[8];
    {
      const int bit = (lane >> 1) & 1;
      #pragma unroll
      for (int q = 0; q < 8; ++q) {
        const float give = bit ? a1[2 * q] : a1[2 * q + 1];
        const float keep = bit ? a1[2 * q + 1] : a1[2 * q];
        a2[q] = keep + __shfl_xor(give, 2);
      }
    }
    float a3[4];
    {
      const int bit = (lane >> 2) & 1;
      #pragma unroll
      for (int q = 0; q < 4; ++q) {
        const float give = bit ? a2[2 * q] : a2[2 * q + 1];
        const float keep = bit ? a2[2 * q + 1] : a2[2 * q];
        a3[q] = keep + __shfl_xor(give, 4);
      }
    }
    float a4[2];
    {
      const int bit = (lane >> 3) & 1;
      #pragma unroll
      for (int q = 0; q < 2; ++q) {
        const float give = bit ? a3[2 * q] : a3[2 * q + 1];
        const float keep = bit ? a3[2 * q + 1] : a3[2 * q];
        a4[q] = keep + __shfl_xor(give, 8);
      }
    }
    float a5;
    {
      const int bit = (lane >> 4) & 1;
      const float give = bit ? a4[0] : a4[1];
      const float keep = bit ? a4[1] : a4[0];
      a5 = keep + __shfl_xor(give, 16);
    }
    const float r = a5 + __shfl_xor(a5, 32);  // full 64-lane sum of index lane&31

    if (lane < 32) {
      const float s = tanhf(r + my_bias);
      // d_out is both the result and the h-exchange medium.
      float* dst = out + (size_t)(t * NB + nbase + onn) * HS + (jbase + w * 8 + ojj);
      __hip_atomic_store(dst, s, __ATOMIC_RELAXED, __HIP_MEMORY_SCOPE_AGENT);
    }
    __syncthreads();  // (e) drains vmcnt(0): all slice stores complete before flag

    if (tid == 0) {
      __hip_atomic_store(
          &flags[((size_t)(g * FLAG_SLOTS + (t & (FLAG_SLOTS - 1))) << 5) + wg],
          (unsigned int)(t + 1), __ATOMIC_RELEASE, __HIP_MEMORY_SCOPE_AGENT);
    }
  }
}

extern "C" void kernel_launch(void* const* d_in, const int* in_sizes, int n_in,
                              void* d_out, int out_size, void* d_ws, size_t ws_size,
                              hipStream_t stream) {
  const float* x     = (const float*)d_in[0];
  const float* h0    = (const float*)d_in[1];
  const float* W_in  = (const float*)d_in[2];
  const float* bias  = (const float*)d_in[3];
  const float* W_h   = (const float*)d_in[4];
  float* out = (float*)d_out;
  unsigned int* flags = (unsigned int*)d_ws;  // 8*64*32*4 = 64 KB of ws; poison-safe

  hipLaunchKernelGGL(reservoir_scan, dim3(NGROUPS * WPG), dim3(NTHREADS), 0, stream,
                     x, h0, W_in, bias, W_h, out, flags);
}

// Round 4
// 12364.420 us; speedup vs baseline: 1.5793x; 1.5655x over previous
//
#include <hip/hip_runtime.h>
#include <stdint.h>

#define LSTEPS 2048
#define NB 32
#define IS 128
#define HS 1024
#define NGROUPS 8      // one per XCD (blockIdx % 8 round-robin)
#define WPG 32         // workgroups per group
#define BPG 4          // batch elements per group
#define CPW 32         // hidden columns per WG
#define NTHREADS 256
#define FLAG_SLOTS 64  // flag ring; exact-value match makes reuse safe (skew <= 1 step)

__global__ __launch_bounds__(NTHREADS, 1)
void reservoir_scan(const float* __restrict__ x,
                    const float* __restrict__ h_init,
                    const float* __restrict__ W_in,
                    const float* __restrict__ bias,
                    const float* __restrict__ W_h,
                    float* __restrict__ out,
                    unsigned int* __restrict__ flags) {
  const int b    = blockIdx.x;
  const int g    = b & 7;     // group (likely = XCD)
  const int wg   = b >> 3;    // 0..31 within group
  const int tid  = threadIdx.x;
  const int w    = tid >> 6;  // wave 0..3  (owns 8 hidden cols)
  const int lane = tid & 63;  // k-split lane
  const int jbase = wg * CPW; // hidden-col base of this WG
  const int nbase = g * BPG;  // batch base of this group

  // LDS (149.5 KB of the 160 KB/CU, 1 WG/CU):
  //   wh_lds [32][1024]  128 KB  -- this WG's W_h row slice, resident all steps
  //   h_lds  [4][1024]    16 KB  -- h(t-1) exchange buffer
  //   x_lds  [4][128]      2 KB
  __shared__ __align__(16) float wh_lds[CPW * HS];
  __shared__ __align__(16) float h_lds[BPG * HS];
  __shared__ __align__(16) float x_lds[BPG * IS];

  // ---- stage W_h slice into LDS once (coalesced float4); visible at barrier (b) of t=0 ----
  for (int e = tid * 4; e < CPW * HS; e += NTHREADS * 4)
    *(float4*)&wh_lds[e] = *(const float4*)&W_h[(size_t)jbase * HS + e];

  float2 wireg[8];
  #pragma unroll
  for (int jj = 0; jj < 8; ++jj)
    wireg[jj] = *(const float2*)&W_in[(size_t)(jbase + w * 8 + jj) * IS + lane * 2];

  // After the butterfly reduce, lane L holds output index i = L&31: nn = i>>3, jj = i&7.
  const int onn = (lane & 31) >> 3;
  const int ojj = lane & 7;
  const float my_bias = bias[jbase + w * 8 + ojj];

  #pragma unroll 1
  for (int t = 0; t < LSTEPS; ++t) {
    // ---- stage x(t) early: independent of flags ----
    {
      const float* xsrc = x + (size_t)(t * NB + nbase) * IS;
      for (int e = tid; e < BPG * IS; e += NTHREADS)
        x_lds[e] = xsrc[e];
    }

    // ---- wait for all 32 producers of step t-1 (all waves spin) ----
    if (t > 0) {
      const unsigned int target = (unsigned int)t;  // value written for step t-1
      const unsigned int* fl =
          flags + ((size_t)(g * FLAG_SLOTS + ((t - 1) & (FLAG_SLOTS - 1))) << 5);
      for (;;) {
        unsigned int v = (lane < WPG)
            ? __hip_atomic_load(&fl[lane], __ATOMIC_RELAXED, __HIP_MEMORY_SCOPE_AGENT)
            : target;
        if (__all(v == target)) break;
        __builtin_amdgcn_s_sleep(1);
      }
      // ---- h(t-1) reload: TWO-PHASE so the 16 agent loads pipeline into ~1 round trip.
      // (Round 0-2 fused load->ds_write per element = 16 serialized MALL round trips
      //  = the ~19k stall cycles/step that dominated every previous kernel.)
      const float* hsrc = out + (size_t)((t - 1) * NB + nbase) * HS;
      float hv[16];
      #pragma unroll
      for (int i = 0; i < 16; ++i)
        hv[i] = __hip_atomic_load(&hsrc[tid + i * NTHREADS], __ATOMIC_RELAXED,
                                  __HIP_MEMORY_SCOPE_AGENT);
      #pragma unroll
      for (int i = 0; i < 16; ++i)
        h_lds[tid + i * NTHREADS] = hv[i];
    } else {
      const float* hsrc = h_init + (size_t)nbase * HS;
      #pragma unroll
      for (int i = 0; i < 16; ++i)
        h_lds[tid + i * NTHREADS] = hsrc[tid + i * NTHREADS];
    }
    __syncthreads();  // (b) h_lds + x_lds (+ wh_lds at t=0) visible to all waves

    // ---- partial dot products: acc[jj][nn], k split across lanes ----
    float acc[8][4];
    #pragma unroll
    for (int jj = 0; jj < 8; ++jj)
      #pragma unroll
      for (int nn = 0; nn < 4; ++nn) acc[jj][nn] = 0.f;

    {
      float2 xv[4];
      #pragma unroll
      for (int nn = 0; nn < 4; ++nn)
        xv[nn] = *(const float2*)&x_lds[nn * IS + lane * 2];
      #pragma unroll
      for (int jj = 0; jj < 8; ++jj) {
        const float2 wv = wireg[jj];
        #pragma unroll
        for (int nn = 0; nn < 4; ++nn)
          acc[jj][nn] += wv.x * xv[nn].x + wv.y * xv[nn].y;
      }
    }

    #pragma unroll
    for (int u = 0; u < 4; ++u) {
      const int k = u * 256 + lane * 4;
      float4 hv4[4];
      #pragma unroll
      for (int nn = 0; nn < 4; ++nn)
        hv4[nn] = *(const float4*)&h_lds[nn * HS + k];
      #pragma unroll
      for (int jj = 0; jj < 8; ++jj) {
        const float4 wv = *(const float4*)&wh_lds[(w * 8 + jj) * HS + k];
        #pragma unroll
        for (int nn = 0; nn < 4; ++nn) {
          acc[jj][nn] += wv.x * hv4[nn].x;
          acc[jj][nn] += wv.y * hv4[nn].y;
          acc[jj][nn] += wv.z * hv4[nn].z;
          acc[jj][nn] += wv.w * hv4[nn].w;
        }
      }
    }

    // ---- butterfly multi-value reduction: 32 values x 64 lanes -> lane L holds i = L&31 ----
    float a0[32];
    #pragma unroll
    for (int jj = 0; jj < 8; ++jj)
      #pragma unroll
      for (int nn = 0; nn < 4; ++nn)
        a0[nn * 8 + jj] = acc[jj][nn];

    float a1[16];
    {
      const int bit = lane & 1;
      #pragma unroll
      for (int q = 0; q < 16; ++q) {
        const float give = bit ? a0[2 * q] : a0[2 * q + 1];
        const float keep = bit ? a0[2 * q + 1] : a0[2 * q];
        a1[q] = keep + __shfl_xor(give, 1);
      }
    }
    float a2[8];
    {
      const int bit = (lane >> 1) & 1;
      #pragma unroll
      for (int q = 0; q < 8; ++q) {
        const float give = bit ? a1[2 * q] : a1[2 * q + 1];
        const float keep = bit ? a1[2 * q + 1] : a1[2 * q];
        a2[q] = keep + __shfl_xor(give, 2);
      }
    }
    float a3[4];
    {
      const int bit = (lane >> 2) & 1;
      #pragma unroll
      for (int q = 0; q < 4; ++q) {
        const float give = bit ? a2[2 * q] : a2[2 * q + 1];
        const float keep = bit ? a2[2 * q + 1] : a2[2 * q];
        a3[q] = keep + __shfl_xor(give, 4);
      }
    }
    float a4[2];
    {
      const int bit = (lane >> 3) & 1;
      #pragma unroll
      for (int q = 0; q < 2; ++q) {
        const float give = bit ? a3[2 * q] : a3[2 * q + 1];
        const float keep = bit ? a3[2 * q + 1] : a3[2 * q];
        a4[q] = keep + __shfl_xor(give, 8);
      }
    }
    float a5;
    {
      const int bit = (lane >> 4) & 1;
      const float give = bit ? a4[0] : a4[1];
      const float keep = bit ? a4[1] : a4[0];
      a5 = keep + __shfl_xor(give, 16);
    }
    const float r = a5 + __shfl_xor(a5, 32);  // full 64-lane sum of index lane&31

    if (lane < 32) {
      const float s = tanhf(r + my_bias);
      // d_out is both the result and the h-exchange medium.
      float* dst = out + (size_t)(t * NB + nbase + onn) * HS + (jbase + w * 8 + ojj);
      __hip_atomic_store(dst, s, __ATOMIC_RELAXED, __HIP_MEMORY_SCOPE_AGENT);
    }
    __syncthreads();  // (e) drains vmcnt(0): all slice stores complete before flag

    if (tid == 0) {
      __hip_atomic_store(
          &flags[((size_t)(g * FLAG_SLOTS + (t & (FLAG_SLOTS - 1))) << 5) + wg],
          (unsigned int)(t + 1), __ATOMIC_RELEASE, __HIP_MEMORY_SCOPE_AGENT);
    }
  }
}

extern "C" void kernel_launch(void* const* d_in, const int* in_sizes, int n_in,
                              void* d_out, int out_size, void* d_ws, size_t ws_size,
                              hipStream_t stream) {
  const float* x     = (const float*)d_in[0];
  const float* h0    = (const float*)d_in[1];
  const float* W_in  = (const float*)d_in[2];
  const float* bias  = (const float*)d_in[3];
  const float* W_h   = (const float*)d_in[4];
  float* out = (float*)d_out;
  unsigned int* flags = (unsigned int*)d_ws;  // 8*64*32*4 = 64 KB of ws; poison-safe

  hipLaunchKernelGGL(reservoir_scan, dim3(NGROUPS * WPG), dim3(NTHREADS), 0, stream,
                     x, h0, W_in, bias, W_h, out, flags);
}

// Round 5
// 11520.320 us; speedup vs baseline: 1.6950x; 1.0733x over previous
//
#include <hip/hip_runtime.h>
#include <stdint.h>

#define LSTEPS 2048
#define NB 32
#define IS 128
#define HS 1024
#define NGROUPS 8      // one per XCD (blockIdx % 8 round-robin)
#define WPG 32         // workgroups per group
#define BPG 4          // batch elements per group
#define CPW 32         // hidden columns per WG
#define NTHREADS 256
#define FLAG_SLOTS 8   // ring; exact-value match + skew<=1 makes reuse safe

// flags layout (per-consumer replicated lines, decontended):
//   dword index = ((g*FLAG_SLOTS + slot)*WPG + consumer)*32 + producer
//   -> each consumer WG polls its OWN 128B line; producers scatter-store one
//      dword into each of the 32 consumer lines (single wave-store).
// total: 8*8*32*32*4 B = 256 KB of ws.

__global__ __launch_bounds__(NTHREADS, 1)
void reservoir_scan(const float* __restrict__ x,
                    const float* __restrict__ h_init,
                    const float* __restrict__ W_in,
                    const float* __restrict__ bias,
                    const float* __restrict__ W_h,
                    float* __restrict__ out,
                    unsigned int* __restrict__ flags) {
  const int b    = blockIdx.x;
  const int g    = b & 7;     // group (likely = XCD)
  const int wg   = b >> 3;    // 0..31 within group
  const int tid  = threadIdx.x;
  const int w    = tid >> 6;  // wave 0..3  (owns 8 hidden cols)
  const int lane = tid & 63;  // k-split lane
  const int jbase = wg * CPW; // hidden-col base of this WG
  const int nbase = g * BPG;  // batch base of this group

  // LDS (149.5 KB): wh_lds 128 KB resident W_h slice; h_lds 16 KB; x_lds 2 KB.
  __shared__ __align__(16) float wh_lds[CPW * HS];
  __shared__ __align__(16) float h_lds[BPG * HS];
  __shared__ __align__(16) float x_lds[BPG * IS];

  // ---- stage W_h slice into LDS once (coalesced float4); visible at barrier (b) of t=0 ----
  for (int e = tid * 4; e < CPW * HS; e += NTHREADS * 4)
    *(float4*)&wh_lds[e] = *(const float4*)&W_h[(size_t)jbase * HS + e];

  float2 wireg[8];
  #pragma unroll
  for (int jj = 0; jj < 8; ++jj)
    wireg[jj] = *(const float2*)&W_in[(size_t)(jbase + w * 8 + jj) * IS + lane * 2];

  // After the butterfly reduce, lane L holds output index i = L&31: nn = i>>3, jj = i&7.
  const int onn = (lane & 31) >> 3;
  const int ojj = lane & 7;
  const float my_bias = bias[jbase + w * 8 + ojj];

  #pragma unroll 1
  for (int t = 0; t < LSTEPS; ++t) {
    // ---- stage x(t) early: independent of flags ----
    {
      const float* xsrc = x + (size_t)(t * NB + nbase) * IS;
      for (int e = tid; e < BPG * IS; e += NTHREADS)
        x_lds[e] = xsrc[e];
    }

    // ---- wait for all 32 producers of step t-1 (all waves poll OWN flag line) ----
    if (t > 0) {
      const unsigned int target = (unsigned int)t;  // value written for step t-1
      const unsigned int* fl =
          flags + (((size_t)(g * FLAG_SLOTS + ((t - 1) & (FLAG_SLOTS - 1))) * WPG + wg) << 5);
      int tries = 0;
      for (;;) {
        unsigned int v = (lane < WPG)
            ? __hip_atomic_load(&fl[lane], __ATOMIC_RELAXED, __HIP_MEMORY_SCOPE_AGENT)
            : target;
        if (__all(v == target)) break;
        if (++tries > 3) __builtin_amdgcn_s_sleep(1);  // fast-poll first, then back off
      }
      // ---- h(t-1) reload: two-phase (pipelined loads), chunk order rotated by wg
      //      to spread the group's 4 MB/step MALL read burst across lines.
      const float* hsrc = out + (size_t)((t - 1) * NB + nbase) * HS;
      float hv[16];
      #pragma unroll
      for (int i = 0; i < 16; ++i) {
        const int ii = (i + wg) & 15;
        hv[i] = __hip_atomic_load(&hsrc[tid + ii * NTHREADS], __ATOMIC_RELAXED,
                                  __HIP_MEMORY_SCOPE_AGENT);
      }
      #pragma unroll
      for (int i = 0; i < 16; ++i) {
        const int ii = (i + wg) & 15;
        h_lds[tid + ii * NTHREADS] = hv[i];
      }
    } else {
      const float* hsrc = h_init + (size_t)nbase * HS;
      #pragma unroll
      for (int i = 0; i < 16; ++i)
        h_lds[tid + i * NTHREADS] = hsrc[tid + i * NTHREADS];
    }
    __syncthreads();  // (b) h_lds + x_lds (+ wh_lds at t=0) visible to all waves

    // ---- partial dot products: acc[jj][nn], k split across lanes ----
    float acc[8][4];
    #pragma unroll
    for (int jj = 0; jj < 8; ++jj)
      #pragma unroll
      for (int nn = 0; nn < 4; ++nn) acc[jj][nn] = 0.f;

    {
      float2 xv[4];
      #pragma unroll
      for (int nn = 0; nn < 4; ++nn)
        xv[nn] = *(const float2*)&x_lds[nn * IS + lane * 2];
      #pragma unroll
      for (int jj = 0; jj < 8; ++jj) {
        const float2 wv = wireg[jj];
        #pragma unroll
        for (int nn = 0; nn < 4; ++nn)
          acc[jj][nn] += wv.x * xv[nn].x + wv.y * xv[nn].y;
      }
    }

    #pragma unroll
    for (int u = 0; u < 4; ++u) {
      const int k = u * 256 + lane * 4;
      float4 hv4[4];
      #pragma unroll
      for (int nn = 0; nn < 4; ++nn)
        hv4[nn] = *(const float4*)&h_lds[nn * HS + k];
      #pragma unroll
      for (int jj = 0; jj < 8; ++jj) {
        const float4 wv = *(const float4*)&wh_lds[(w * 8 + jj) * HS + k];
        #pragma unroll
        for (int nn = 0; nn < 4; ++nn) {
          acc[jj][nn] += wv.x * hv4[nn].x;
          acc[jj][nn] += wv.y * hv4[nn].y;
          acc[jj][nn] += wv.z * hv4[nn].z;
          acc[jj][nn] += wv.w * hv4[nn].w;
        }
      }
    }

    // ---- butterfly multi-value reduction: 32 values x 64 lanes -> lane L holds i = L&31 ----
    float a0[32];
    #pragma unroll
    for (int jj = 0; jj < 8; ++jj)
      #pragma unroll
      for (int nn = 0; nn < 4; ++nn)
        a0[nn * 8 + jj] = acc[jj][nn];

    float a1[16];
    {
      const int bit = lane & 1;
      #pragma unroll
      for (int q = 0; q < 16; ++q) {
        const float give = bit ? a0[2 * q] : a0[2 * q + 1];
        const float keep = bit ? a0[2 * q + 1] : a0[2 * q];
        a1[q] = keep + __shfl_xor(give, 1);
      }
    }
    float a2[8];
    {
      const int bit = (lane >> 1) & 1;
      #pragma unroll
      for (int q = 0; q < 8; ++q) {
        const float give = bit ? a1[2 * q] : a1[2 * q + 1];
        const float keep = bit ? a1[2 * q + 1] : a1[2 * q];
        a2[q] = keep + __shfl_xor(give, 2);
      }
    }
    float a3[4];
    {
      const int bit = (lane >> 2) & 1;
      #pragma unroll
      for (int q = 0; q < 4; ++q) {
        const float give = bit ? a2[2 * q] : a2[2 * q + 1];
        const float keep = bit ? a2[2 * q + 1] : a2[2 * q];
        a3[q] = keep + __shfl_xor(give, 4);
      }
    }
    float a4[2];
    {
      const int bit = (lane >> 3) & 1;
      #pragma unroll
      for (int q = 0; q < 2; ++q) {
        const float give = bit ? a3[2 * q] : a3[2 * q + 1];
        const float keep = bit ? a3[2 * q + 1] : a3[2 * q];
        a4[q] = keep + __shfl_xor(give, 8);
      }
    }
    float a5;
    {
      const int bit = (lane >> 4) & 1;
      const float give = bit ? a4[0] : a4[1];
      const float keep = bit ? a4[1] : a4[0];
      a5 = keep + __shfl_xor(give, 16);
    }
    const float r = a5 + __shfl_xor(a5, 32);  // full 64-lane sum of index lane&31

    if (lane < 32) {
      const float s = tanhf(r + my_bias);
      // d_out is both the result and the h-exchange medium.
      float* dst = out + (size_t)(t * NB + nbase + onn) * HS + (jbase + w * 8 + ojj);
      __hip_atomic_store(dst, s, __ATOMIC_RELAXED, __HIP_MEMORY_SCOPE_AGENT);
    }
    __syncthreads();  // (e) drains vmcnt(0): all slice stores visible before flags

    // ---- publish: one wave-store scatters this WG's flag into all 32 consumer lines ----
    if (tid < WPG) {
      unsigned int* fp =
          &flags[(((size_t)(g * FLAG_SLOTS + (t & (FLAG_SLOTS - 1))) * WPG + tid) << 5) + wg];
      __hip_atomic_store(fp, (unsigned int)(t + 1), __ATOMIC_RELEASE,
                         __HIP_MEMORY_SCOPE_AGENT);
    }
  }
}

extern "C" void kernel_launch(void* const* d_in, const int* in_sizes, int n_in,
                              void* d_out, int out_size, void* d_ws, size_t ws_size,
                              hipStream_t stream) {
  const float* x     = (const float*)d_in[0];
  const float* h0    = (const float*)d_in[1];
  const float* W_in  = (const float*)d_in[2];
  const float* bias  = (const float*)d_in[3];
  const float* W_h   = (const float*)d_in[4];
  float* out = (float*)d_out;
  unsigned int* flags = (unsigned int*)d_ws;  // 256 KB of ws used; poison-safe (exact-value match)

  hipLaunchKernelGGL(reservoir_scan, dim3(NGROUPS * WPG), dim3(NTHREADS), 0, stream,
                     x, h0, W_in, bias, W_h, out, flags);
}